// Round 1
// 178.706 us; speedup vs baseline: 1.0995x; 1.0995x over previous
//
#include <hip/hip_runtime.h>
#include <stddef.h>

#define N_NODES 10000
#define NE 320000
#define NB 32
#define SIZE1 80000
#define SIZE2 80000
#define CAP 96          // fixed CSR capacity per node; deg ~ Poisson(32), P(>96) ~ 1e-20

// d_ws layout (int offsets)
#define WS_CURSOR 0          // 10000 ints
#define WS_RECS   10000      // ulong recs[N_NODES*CAP] = 1.92M ints (byte off 40000, 8B aligned)
#define WS_XT     1930000    // bf16 xt[N_NODES][32][8] = 1.28M ints (byte off 7720000, 16B aligned)

typedef short short8 __attribute__((ext_vector_type(8)));
typedef float floatx4 __attribute__((ext_vector_type(4)));
union FragU { short8 v; ushort us[8]; uint4 u4; };

__device__ inline ushort f2bf(float f) {
  union { float f; unsigned u; } c; c.f = f;
  unsigned u = c.u;
  u += 0x7fffu + ((u >> 16) & 1u);   // round-to-nearest-even
  return (ushort)(u >> 16);
}

// Build kernel: per edge e -> atomicAdd cursor[row], write one 8B record
// {e, col} to the node's slot list (scattered 8B). Plus the x fp32->bf16
// transpose, LDS-free: task (n,b) = (e>>5, e&31) reads 32B contiguous of x,
// writes 16B granule of xt (wave-coalesced to 1KB stores). No vcsr payload:
// gather reads vals fp32 directly (read exactly once, L3-resident).
__global__ __launch_bounds__(256) void build_kernel(const float* __restrict__ x,
                                                    const int* __restrict__ idxs,
                                                    int* __restrict__ cursor,
                                                    unsigned long long* __restrict__ recs,
                                                    ushort* __restrict__ xt) {
  const int t = threadIdx.x;
  const int e = blockIdx.x * 256 + t;            // NE = 1250*256 exactly
  const int r = idxs[e];
  const int c = idxs[NE + e];
  const int pos = atomicAdd(&cursor[r], 1);
  if (pos < CAP)
    recs[(size_t)r * CAP + pos] = (unsigned long long)(unsigned)e |
                                  ((unsigned long long)(unsigned)c << 32);

  // x transpose: xt[n][b][i] bf16. NE == N_NODES*32 exactly, one task per thread.
  const int n = e >> 5;
  const int b = e & 31;
  const float* xp = x + (size_t)b * SIZE1 + n * 8;
  float4 v0 = *(const float4*)xp;
  float4 v1 = *(const float4*)(xp + 4);
  FragU f;
  f.us[0] = f2bf(v0.x); f.us[1] = f2bf(v0.y); f.us[2] = f2bf(v0.z); f.us[3] = f2bf(v0.w);
  f.us[4] = f2bf(v1.x); f.us[5] = f2bf(v1.y); f.us[6] = f2bf(v1.z); f.us[7] = f2bf(v1.w);
  *(uint4*)(xt + (size_t)n * 256 + b * 8) = f.u4;
}

// ONE WAVE PER NODE (4 nodes per 256-block). No LDS, no cross-wave reduction.
// Per 4-edge slot: quad q handles edge s*4+q; A-frags (x rows) come from bf16
// xt (256B contiguous per quad), B-frag is built in-register from fp32 vals
// (8 strided dwords on lanes nn<8, f2bf convert) -> j-major fragment.
__global__ __launch_bounds__(256) void gather_mfma_kernel(const ushort* __restrict__ xt,
                                                          const float* __restrict__ vals,
                                                          const float* __restrict__ bias,
                                                          const int* __restrict__ cursor,
                                                          const unsigned long long* __restrict__ recs,
                                                          float* __restrict__ out) {
  const int t = threadIdx.x;
  const int lane = t & 63;
  const int w = t >> 6;              // wave id 0..3
  const int n = blockIdx.x * 4 + w;  // node for this wave
  const int quad = lane >> 4;
  const int nn = lane & 15;
  const int deg = min(cursor[n], CAP);
  const size_t nbase = (size_t)n * CAP;

  floatx4 acc0 = {0.f, 0.f, 0.f, 0.f};
  floatx4 acc1 = {0.f, 0.f, 0.f, 0.f};

  for (int base = 0; base < deg; base += 64) {
    const int lim = min(64, deg - base);                       // edges this chunk
    const unsigned long long rv = recs[nbase + base + min(lane, lim - 1)];  // coalesced
    const int elo = (int)(unsigned)rv;                         // edge id
    const int ehi = (int)(unsigned)(rv >> 32);                 // col (x node)
    const int nslots = (lim + 3) >> 2;                         // 4-edge slots

    for (int s = 0; s < nslots; s += 2) {
      FragU alo0, ahi0, b0, alo1, ahi1, b1;
      {
        const int le = s * 4 + quad;
        const int lec = min(le, lim - 1);
        const int eid = __shfl(elo, lec);
        const int px  = __shfl(ehi, lec);
        const ushort* xr = xt + (size_t)px * 256;
        alo0.u4 = *(const uint4*)(xr + nn * 8);                // b = nn
        ahi0.u4 = *(const uint4*)(xr + 128 + nn * 8);          // b = nn+16
        b0.u4 = make_uint4(0, 0, 0, 0);
        if (nn < 8 && le < lim) {
          const float* vp = vals + (size_t)eid * 64 + nn;      // column j = nn
#pragma unroll
          for (int i = 0; i < 8; ++i) b0.us[i] = f2bf(vp[i * 8]);
        }
      }
      {
        const int le = (s + 1) * 4 + quad;
        const int lec = min(le, lim - 1);
        const int eid = __shfl(elo, lec);
        const int px  = __shfl(ehi, lec);
        const ushort* xr = xt + (size_t)px * 256;
        alo1.u4 = *(const uint4*)(xr + nn * 8);
        ahi1.u4 = *(const uint4*)(xr + 128 + nn * 8);
        b1.u4 = make_uint4(0, 0, 0, 0);
        if (nn < 8 && le < lim) {
          const float* vp = vals + (size_t)eid * 64 + nn;
#pragma unroll
          for (int i = 0; i < 8; ++i) b1.us[i] = f2bf(vp[i * 8]);
        }
      }
      acc0 = __builtin_amdgcn_mfma_f32_16x16x32_bf16(alo0.v, b0.v, acc0, 0, 0, 0);
      acc1 = __builtin_amdgcn_mfma_f32_16x16x32_bf16(ahi0.v, b0.v, acc1, 0, 0, 0);
      acc0 = __builtin_amdgcn_mfma_f32_16x16x32_bf16(alo1.v, b1.v, acc0, 0, 0, 0);
      acc1 = __builtin_amdgcn_mfma_f32_16x16x32_bf16(ahi1.v, b1.v, acc1, 0, 0, 0);
    }
  }

  // C/D: col(j) = lane&15, row(b) = quad*4 + reg. Each wave writes its node.
  if (nn < 8) {
    const float bz = bias[n * 8 + nn];
#pragma unroll
    for (int r = 0; r < 4; ++r) {
      out[(size_t)(quad * 4 + r) * SIZE2 + n * 8 + nn] = acc0[r] + bz;
      out[(size_t)(16 + quad * 4 + r) * SIZE2 + n * 8 + nn] = acc1[r] + bz;
    }
  }
}

extern "C" void kernel_launch(void* const* d_in, const int* in_sizes, int n_in,
                              void* d_out, int out_size, void* d_ws, size_t ws_size,
                              hipStream_t stream) {
  const float* x    = (const float*)d_in[0];
  const float* vals = (const float*)d_in[1];
  const float* bias = (const float*)d_in[2];
  const int*   idxs = (const int*)d_in[3];
  float* out = (float*)d_out;

  int* ws = (int*)d_ws;
  int* cursor = ws + WS_CURSOR;
  unsigned long long* recs = (unsigned long long*)(ws + WS_RECS);
  ushort* xt = (ushort*)(ws + WS_XT);

  hipMemsetAsync(cursor, 0, N_NODES * sizeof(int), stream);

  build_kernel<<<NE / 256, 256, 0, stream>>>(x, idxs, cursor, recs, xt);
  gather_mfma_kernel<<<N_NODES / 4, 256, 0, stream>>>(xt, vals, bias, cursor, recs, out);
}